// Round 2
// baseline (38.881 us; speedup 1.0000x reference)
//
#include <hip/hip_runtime.h>
#include <math.h>

namespace {

constexpr int KD = 128;   // K * D floats per class row
constexpr int DH = 32;    // half-dim
constexpr int Bn = 512;
constexpr int Pn = 2048;
constexpr int PCHUNK = 256;   // points per block (1 per thread)
constexpr int NB = 4;         // batch rows per block (amortize point loads)
constexpr int GX = Pn / PCHUNK;  // 8
constexpr int GY = Bn / NB;      // 128
constexpr int NBLK = GX * GY;    // 1024
constexpr float MC_MULT_F = 4.0f / 2048.0f;
constexpr float EPS_F = 1e-9f;
constexpr double SCALE = 8388608.0;  // 2^23 fixed-point scale

__global__ __launch_bounds__(256, 4) void mbel_fused(
    const float* __restrict__ cw,   // (C, 128)
    const float* __restrict__ mc,   // (P, 32)
    const int*   __restrict__ nf1,  // (B, 2)
    float* __restrict__ out,        // scalar
    unsigned long long* __restrict__ ws)  // [0]=acc(i64 fixed), [1]=counter
{
    __shared__ float s_red[4];
    const int tid = threadIdx.x;
    const int p   = blockIdx.x * PCHUNK + tid;
    const int b0  = blockIdx.y * NB;

    // block-uniform class indices -> force SGPR so class rows become s_loads
    int idxs[NB][2];
    #pragma unroll
    for (int j = 0; j < NB; ++j) {
        idxs[j][0] = __builtin_amdgcn_readfirstlane(nf1[(b0 + j) * 2 + 0]);
        idxs[j][1] = __builtin_amdgcn_readfirstlane(nf1[(b0 + j) * 2 + 1]);
    }

    const float4* mp = reinterpret_cast<const float4*>(mc + (size_t)p * DH);
    float pt[8];
    {
        float4 v0 = mp[0], v1 = mp[1];
        pt[0]=v0.x; pt[1]=v0.y; pt[2]=v0.z; pt[3]=v0.w;
        pt[4]=v1.x; pt[5]=v1.y; pt[6]=v1.z; pt[7]=v1.w;
    }

    // partial margins over dims 0..7:  min_d( |off| - |p - cen| )
    // (identical op order to the full chain's first 8 steps -> bit-exact resume)
    float m[NB][2][2];
    bool easy = true;
    #pragma unroll
    for (int j = 0; j < NB; ++j) {
        #pragma unroll
        for (int e = 0; e < 2; ++e) {
            const float* row = cw + (size_t)idxs[j][e] * KD;
            #pragma unroll
            for (int k = 0; k < 2; ++k) {
                const float* box = row + k * 64;
                float mm = 3.402823466e38f;
                #pragma unroll
                for (int d = 0; d < 8; ++d) {
                    float mg = fabsf(box[DH + d]) - fabsf(pt[d] - box[d]);
                    mm = fminf(mm, mg);
                }
                m[j][e][k] = mm;
                easy = easy && (mm <= 0.0f);
            }
        }
    }

    // If every (j,e,k) partial min is already <= 0, the full min is <= 0,
    // so sigmoid(margin) <= 0.5 for both classes => area1 = inter = 0
    // => term == 1.0f EXACTLY in f32. Skip dims 8..31 entirely.
    float tsum;
    if (__all(easy)) {
        tsum = (float)NB;
    } else {
        float pt2[24];
        #pragma unroll
        for (int q = 0; q < 6; ++q) {
            float4 v = mp[2 + q];
            pt2[4*q+0]=v.x; pt2[4*q+1]=v.y; pt2[4*q+2]=v.z; pt2[4*q+3]=v.w;
        }
        tsum = 0.0f;
        #pragma unroll
        for (int j = 0; j < NB; ++j) {
            float inc[2];
            #pragma unroll
            for (int e = 0; e < 2; ++e) {
                const float* row = cw + (size_t)idxs[j][e] * KD;
                float best = -3.402823466e38f;
                #pragma unroll
                for (int k = 0; k < 2; ++k) {
                    const float* box = row + k * 64;
                    float mm = m[j][e][k];
                    #pragma unroll
                    for (int d = 8; d < DH; ++d) {
                        float mg = fabsf(box[DH + d]) - fabsf(pt2[d - 8] - box[d]);
                        mm = fminf(mm, mg);
                    }
                    best = fmaxf(best, mm);
                }
                inc[e] = 1.0f / (1.0f + expf(-best));
            }
            float area1 = fmaxf(inc[0] - 0.5f, 0.0f) * MC_MULT_F;
            float inter = fmaxf((inc[0] + inc[1]) * 0.5f - 0.5f, 0.0f) * MC_MULT_F;
            tsum += 1.0f - inter / (area1 + EPS_F);
        }
    }

    // deterministic block reduction: wave64 shfl tree + 4-wave LDS combine
    float v = tsum;
    #pragma unroll
    for (int off = 32; off > 0; off >>= 1) v += __shfl_down(v, off, 64);
    const int lane = tid & 63, wid = tid >> 6;
    if (lane == 0) s_red[wid] = v;
    __syncthreads();
    if (tid == 0) {
        float t = s_red[0] + s_red[1] + s_red[2] + s_red[3];
        // fixed-point (2^23) int64 accumulation: associative => deterministic
        long long q = (long long)llrint((double)t * SCALE);
        atomicAdd(&ws[0], (unsigned long long)q);
        __threadfence();
        unsigned int* cnt = (unsigned int*)(ws + 1);
        unsigned int done = atomicAdd(cnt, 1u);
        if (done == (unsigned int)(NBLK - 1)) {
            __threadfence();
            unsigned long long raw = atomicAdd(&ws[0], 0ull);
            double total = (double)(long long)raw * (1.0 / SCALE);
            float loss = (float)(total * (1.0 / ((double)Bn * (double)Pn)));
            out[0] = fmaxf(loss, 0.0f);
        }
    }
}

} // namespace

extern "C" void kernel_launch(void* const* d_in, const int* in_sizes, int n_in,
                              void* d_out, int out_size, void* d_ws, size_t ws_size,
                              hipStream_t stream) {
    const float* cw  = (const float*)d_in[0];  // class_weight (C, 128) f32
    const float* mc  = (const float*)d_in[1];  // mc_points (P, 32) f32
    const int*   nf1 = (const int*)d_in[2];    // nf1_data (B, 2) i32
    float* out = (float*)d_out;
    unsigned long long* ws = (unsigned long long*)d_ws;

    // zero acc + counter each call (d_ws is poisoned, not re-poisoned between replays)
    hipMemsetAsync(ws, 0, 16, stream);
    dim3 grid(GX, GY);  // (8, 128) = 1024 blocks, fully co-resident
    mbel_fused<<<grid, 256, 0, stream>>>(cw, mc, nf1, out, ws);
}

// Round 3
// 29.558 us; speedup vs baseline: 1.3154x; 1.3154x over previous
//
#include <hip/hip_runtime.h>
#include <math.h>

namespace {

constexpr int KD = 128;   // K * D floats per class row
constexpr int DH = 32;    // half-dim
constexpr int Bn = 512;
constexpr int Pn = 2048;
constexpr int TPB = 256;
constexpr int PPT = Pn / TPB;   // 8 points per thread
constexpr int NBLK = Bn;        // one block per batch row
constexpr float MC_MULT_F = 4.0f / 2048.0f;
constexpr float EPS_F = 1e-9f;
constexpr double SCALE = 8388608.0;  // 2^23 fixed-point scale

__global__ __launch_bounds__(TPB) void mbel_fused(
    const float* __restrict__ cw,   // (C, 128)
    const float* __restrict__ mc,   // (P, 32)
    const int*   __restrict__ nf1,  // (B, 2)
    float* __restrict__ out,        // scalar
    unsigned long long* __restrict__ ws)  // [0]=acc(i64 fixed), [1]=counter
{
    __shared__ float s_cw[2 * KD];  // class-c row then class-d row
    __shared__ float s_red[4];

    const int tid = threadIdx.x;
    const int b   = blockIdx.x;

    // stage both class rows: one load per thread, coalesced gather
    {
        const int idx0 = nf1[2 * b + 0];
        const int idx1 = nf1[2 * b + 1];
        const int cls  = (tid < KD) ? idx0 : idx1;
        s_cw[tid] = cw[(size_t)cls * KD + (tid & (KD - 1))];
    }
    __syncthreads();

    // hoist fast-path box constants (dims 0..7) into registers, reused 8x
    float fc[4][8], fo[4][8];
    #pragma unroll
    for (int be = 0; be < 4; ++be) {
        const int base = (be >> 1) * KD + (be & 1) * 64;
        #pragma unroll
        for (int d = 0; d < 8; ++d) {
            fc[be][d] = s_cw[base + d];
            fo[be][d] = fabsf(s_cw[base + DH + d]);
        }
    }

    float tsum = 0.0f;
    for (int i = 0; i < PPT; ++i) {
        const int p = i * TPB + tid;
        const float4* mp = reinterpret_cast<const float4*>(mc + (size_t)p * DH);
        float4 v0 = mp[0], v1 = mp[1];
        float pt[8] = {v0.x, v0.y, v0.z, v0.w, v1.x, v1.y, v1.z, v1.w};

        // partial margins over dims 0..7 (same op order as the full chain)
        float m[4];
        bool easy = true;
        #pragma unroll
        for (int be = 0; be < 4; ++be) {
            float mm = 3.402823466e38f;
            #pragma unroll
            for (int d = 0; d < 8; ++d)
                mm = fminf(mm, fo[be][d] - fabsf(pt[d] - fc[be][d]));
            m[be] = mm;
            easy = easy && (mm <= 0.0f);
        }

        // all 4 boxes' partial mins <= 0 (whole wave) => every lane's term
        // is exactly 1.0f (sigmoid<=0.5 => both areas exactly 0)
        if (__all(easy)) { tsum += 1.0f; continue; }

        // slow path: finish dims 8..31 from LDS; easy lanes yield exactly 1.0
        float pt2[24];
        #pragma unroll
        for (int q = 0; q < 6; ++q) {
            float4 v = mp[2 + q];
            pt2[4*q+0] = v.x; pt2[4*q+1] = v.y;
            pt2[4*q+2] = v.z; pt2[4*q+3] = v.w;
        }
        float inc[2];
        #pragma unroll
        for (int e = 0; e < 2; ++e) {
            float best = -3.402823466e38f;
            #pragma unroll
            for (int k = 0; k < 2; ++k) {
                const float* box = s_cw + e * KD + k * 64;
                float mm = m[e * 2 + k];
                #pragma unroll
                for (int d = 8; d < DH; ++d)
                    mm = fminf(mm, fabsf(box[DH + d]) - fabsf(pt2[d - 8] - box[d]));
                best = fmaxf(best, mm);
            }
            inc[e] = 1.0f / (1.0f + expf(-best));
        }
        float area1 = fmaxf(inc[0] - 0.5f, 0.0f) * MC_MULT_F;
        float inter = fmaxf((inc[0] + inc[1]) * 0.5f - 0.5f, 0.0f) * MC_MULT_F;
        tsum += 1.0f - inter / (area1 + EPS_F);
    }

    // deterministic block reduction: wave64 shfl tree + 4-wave LDS combine
    float v = tsum;
    #pragma unroll
    for (int off = 32; off > 0; off >>= 1) v += __shfl_down(v, off, 64);
    const int lane = tid & 63, wid = tid >> 6;
    if (lane == 0) s_red[wid] = v;
    __syncthreads();
    if (tid == 0) {
        float t = s_red[0] + s_red[1] + s_red[2] + s_red[3];
        // fixed-point (2^23) int64 accumulation: associative => deterministic
        long long q = (long long)llrint((double)t * SCALE);
        atomicAdd(&ws[0], (unsigned long long)q);
        __threadfence();
        unsigned int* cnt = (unsigned int*)(ws + 1);
        unsigned int done = atomicAdd(cnt, 1u);
        if (done == (unsigned int)(NBLK - 1)) {
            __threadfence();
            unsigned long long raw = atomicAdd(&ws[0], 0ull);
            double total = (double)(long long)raw * (1.0 / SCALE);
            float loss = (float)(total * (1.0 / ((double)Bn * (double)Pn)));
            out[0] = fmaxf(loss, 0.0f);
        }
    }
}

} // namespace

extern "C" void kernel_launch(void* const* d_in, const int* in_sizes, int n_in,
                              void* d_out, int out_size, void* d_ws, size_t ws_size,
                              hipStream_t stream) {
    const float* cw  = (const float*)d_in[0];  // class_weight (C, 128) f32
    const float* mc  = (const float*)d_in[1];  // mc_points (P, 32) f32
    const int*   nf1 = (const int*)d_in[2];    // nf1_data (B, 2) i32
    float* out = (float*)d_out;
    unsigned long long* ws = (unsigned long long*)d_ws;

    // zero acc + counter each call (d_ws is poisoned, not re-poisoned between replays)
    hipMemsetAsync(ws, 0, 16, stream);
    mbel_fused<<<NBLK, TPB, 0, stream>>>(cw, mc, nf1, out, ws);
}

// Round 4
// 17.585 us; speedup vs baseline: 2.2110x; 1.6808x over previous
//
#include <hip/hip_runtime.h>
#include <math.h>

namespace {

constexpr int KD = 128;   // K * D floats per class row
constexpr int DH = 32;    // half-dim
constexpr int Bn = 512;
constexpr int Pn = 2048;
constexpr int TPB = 256;
constexpr int PPT = Pn / TPB;   // 8 points per thread
constexpr int NBLK = Bn;        // one block per batch row
constexpr float MC_MULT_F = 4.0f / 2048.0f;
constexpr float EPS_F = 1e-9f;

__global__ __launch_bounds__(TPB) void mbel_main(
    const float* __restrict__ cw,   // (C, 128)
    const float* __restrict__ mc,   // (P, 32)
    const int*   __restrict__ nf1,  // (B, 2)
    float* __restrict__ partial)    // (NBLK) — every slot overwritten each call
{
    __shared__ float s_cw[2 * KD];  // class-c row then class-d row
    __shared__ float s_red[4];

    const int tid = threadIdx.x;
    const int b   = blockIdx.x;

    // stage both class rows: one load per thread, coalesced gather
    {
        const int idx0 = nf1[2 * b + 0];
        const int idx1 = nf1[2 * b + 1];
        const int cls  = (tid < KD) ? idx0 : idx1;
        s_cw[tid] = cw[(size_t)cls * KD + (tid & (KD - 1))];
    }
    __syncthreads();

    // hoist fast-path box constants (dims 0..7) into registers, reused 8x
    float fc[4][8], fo[4][8];
    #pragma unroll
    for (int be = 0; be < 4; ++be) {
        const int base = (be >> 1) * KD + (be & 1) * 64;
        #pragma unroll
        for (int d = 0; d < 8; ++d) {
            fc[be][d] = s_cw[base + d];
            fo[be][d] = fabsf(s_cw[base + DH + d]);
        }
    }

    float tsum = 0.0f;
    for (int i = 0; i < PPT; ++i) {
        const int p = i * TPB + tid;
        const float4* mp = reinterpret_cast<const float4*>(mc + (size_t)p * DH);
        float4 v0 = mp[0], v1 = mp[1];
        float pt[8] = {v0.x, v0.y, v0.z, v0.w, v1.x, v1.y, v1.z, v1.w};

        // partial margins over dims 0..7 (same op order as the full chain)
        float m[4];
        bool easy = true;
        #pragma unroll
        for (int be = 0; be < 4; ++be) {
            float mm = 3.402823466e38f;
            #pragma unroll
            for (int d = 0; d < 8; ++d)
                mm = fminf(mm, fo[be][d] - fabsf(pt[d] - fc[be][d]));
            m[be] = mm;
            easy = easy && (mm <= 0.0f);
        }

        // all 4 boxes' partial mins <= 0 (whole wave) => every lane's term
        // is exactly 1.0f (sigmoid<=0.5 => both areas exactly 0)
        if (__all(easy)) { tsum += 1.0f; continue; }

        // slow path: finish dims 8..31 from LDS; easy lanes yield exactly 1.0
        float pt2[24];
        #pragma unroll
        for (int q = 0; q < 6; ++q) {
            float4 v = mp[2 + q];
            pt2[4*q+0] = v.x; pt2[4*q+1] = v.y;
            pt2[4*q+2] = v.z; pt2[4*q+3] = v.w;
        }
        float inc[2];
        #pragma unroll
        for (int e = 0; e < 2; ++e) {
            float best = -3.402823466e38f;
            #pragma unroll
            for (int k = 0; k < 2; ++k) {
                const float* box = s_cw + e * KD + k * 64;
                float mm = m[e * 2 + k];
                #pragma unroll
                for (int d = 8; d < DH; ++d)
                    mm = fminf(mm, fabsf(box[DH + d]) - fabsf(pt2[d - 8] - box[d]));
                best = fmaxf(best, mm);
            }
            inc[e] = 1.0f / (1.0f + expf(-best));
        }
        float area1 = fmaxf(inc[0] - 0.5f, 0.0f) * MC_MULT_F;
        float inter = fmaxf((inc[0] + inc[1]) * 0.5f - 0.5f, 0.0f) * MC_MULT_F;
        tsum += 1.0f - inter / (area1 + EPS_F);
    }

    // deterministic block reduction: wave64 shfl tree + 4-wave LDS combine
    float v = tsum;
    #pragma unroll
    for (int off = 32; off > 0; off >>= 1) v += __shfl_down(v, off, 64);
    const int lane = tid & 63, wid = tid >> 6;
    if (lane == 0) s_red[wid] = v;
    __syncthreads();
    if (tid == 0)
        partial[b] = s_red[0] + s_red[1] + s_red[2] + s_red[3];
}

// single-wave finalize: 512 floats -> scalar, fixed-order, no LDS/atomics
__global__ __launch_bounds__(64) void mbel_final(
    const float* __restrict__ partial, float* __restrict__ out)
{
    const int t = threadIdx.x;  // 0..63
    const float4* p4 = reinterpret_cast<const float4*>(partial);
    float4 a = p4[t], bq = p4[t + 64];
    float v = ((a.x + a.y) + (a.z + a.w)) + ((bq.x + bq.y) + (bq.z + bq.w));
    #pragma unroll
    for (int off = 32; off > 0; off >>= 1) v += __shfl_down(v, off, 64);
    if (t == 0) {
        float loss = v * (1.0f / ((float)Bn * (float)Pn));
        out[0] = fmaxf(loss, 0.0f);
    }
}

} // namespace

extern "C" void kernel_launch(void* const* d_in, const int* in_sizes, int n_in,
                              void* d_out, int out_size, void* d_ws, size_t ws_size,
                              hipStream_t stream) {
    const float* cw  = (const float*)d_in[0];  // class_weight (C, 128) f32
    const float* mc  = (const float*)d_in[1];  // mc_points (P, 32) f32
    const int*   nf1 = (const int*)d_in[2];    // nf1_data (B, 2) i32
    float* out = (float*)d_out;
    float* partial = (float*)d_ws;             // 512 floats, fully overwritten

    mbel_main<<<NBLK, TPB, 0, stream>>>(cw, mc, nf1, partial);
    mbel_final<<<1, 64, 0, stream>>>(partial, out);
}